// Round 10
// baseline (103.295 us; speedup 1.0000x reference)
//
#include <hip/hip_runtime.h>
#include <math.h>

// EKF over 2048 trajectories, T=512 serial steps; lane 3k+j = subsystem j of
// trajectory k (21 traj/wave), three independent 2-state/1-meas Kalman
// filters per trajectory. Latency-bound serial chain; wall = 512 x per-step.
//
// R14: producer/consumer wave specialization (~41 us warm).
// R15: z pre-scaled, posC'=fma(-r,rsyC,zC), Mahalanobis in service. flat.
// R16: single-rcp fusion (23 VALU + 2 trans). flat -> trans issue at ~VALU
// cost for a solo wave; per-step ~= 41 ns issue + ~38 ns latency/boundary.
//
// R17 (this round): tile-boundary smoothing - the last controllable term.
//  (1) all 8 z float4s prefetched into registers at tile top (one lgkmcnt
//      drain; no per-quad ds_read exposure mid-tile);
//  (2) (S,y) written inline as one ds_write_b128 per 2 steps (replaces the
//      16-write end-of-tile burst; same op count, no cluster);
//  (3) s_setprio(1) on the compute wave (free; pays iff sharing a SIMD).
// Step math bit-identical to R16. If flat: declare roofline (issue cadence +
// carried chain; all structural levers measured null).

#define TRIPLES 21
#define TILE    32
#define SMS4    17               // sSM row stride in float4 (16 pairs + 1 pad)

__device__ __forceinline__ float frcp(float x) { return __builtin_amdgcn_rcpf(x); }

__global__ __launch_bounds__(128, 1) void ekf_kernel(
    const float* __restrict__ meas,        // (n_traj, T, 3)
    const float* __restrict__ init_state,  // (n_traj, 6)
    const float* __restrict__ dyna,        // (4,)
    const float* __restrict__ Qm,          // (6,6)
    const float* __restrict__ Rm,          // (3,3)
    const float* __restrict__ P0m,         // (6,6)
    float* __restrict__ out,               // (n_traj*T,)
    int n_traj, int T)
{
    // z tiles (pre-scaled by Cc): [buf][t-chunk][compute-lane] float4 = 16 KB.
    __shared__ float4 zs4[2][TILE / 4][64];
    // (S,y) pairs: [buf][72 rows x SMS4] float4 = 39.2 KB (flush round rr=5
    // reads rows up to 71; stores guarded, reads in-bounds, rows>=63 garbage).
    __shared__ float4 sSM4[2][72 * SMS4];

    const int tid   = threadIdx.x;
    const int wid   = tid >> 6;            // 0 = compute, 1 = service
    const int lane  = tid & 63;
    const int k     = lane / 3;
    const int j     = lane - 3 * k;        // subsystem 0=x,1=y,2=theta
    const int traj0 = blockIdx.x * TRIPLES;
    const int kk    = (k < TRIPLES) ? k : (TRIPLES - 1);
    const int traj  = traj0 + kk;
    const int traj_eff = (traj < n_traj) ? traj : (n_traj - 1);

    const int NT = T / TILE;               // 16
    const int T3 = 3 * T;

    if (wid == 0) __builtin_amdgcn_s_setprio(1);   // favor the chain wave

    // ---- filter constants (theta block is linear: ca=1, cf=0) ----
    const float DTc = 1.0f / 120.0f;
    const float Cc  = 288.53900817779268f; // 200/ln2
    const float invCc2 = 1.0f / (Cc * Cc);
    const float fric = dyna[0], damp = dyna[1];
    const bool  lin = (j == 2);
    const float ca  = lin ? 1.0f : (1.0f - DTc * damp);
    const float cf  = lin ? 0.0f : (DTc * fric);
    const float cb  = 100.0f * cf;
    const float m4cb  = -4.0f * cb;
    const float cf2Cc = 2.0f * (cf * Cc);
    const float mcfCc = -(cf * Cc);
    const int pi = (j == 0) ? 0 : (j == 1) ? 1 : 4;
    const int vi = lin ? 5 : (pi + 2);     // theta velocity is state 5
    const float qp = Qm[pi * 7], qv = Qm[vi * 7], qc = Qm[pi * 6 + vi];
    const float r   = Rm[j * 4];
    const float nr2 = -r * r;
    const float w0  = r + r + qp;          // w' = nr2*rs + w0
    float p02 = P0m[pi * 6 + vi], p22 = P0m[vi * 7];
    float w   = P0m[pi * 7] + qp + r;      // w = p00 + qp + r (carried)
    float posC = Cc * init_state[traj_eff * 6 + pi];
    float xv   = Cc * init_state[traj_eff * 6 + vi];

    // ---- service-side invariants ----
    const int fh = lane >> 4;              // 0..3 traj row within flush round
    const int tw = lane & 15;              // t-pair index
    const int fb0 = (3 * fh) * SMS4 + tw;  // float4 index, rr=0, subsys 0
    float* const obase = out + (size_t)(traj0 + fh) * T + 2 * tw;
    const float* __restrict__ zlane = meas + (size_t)traj_eff * T3 + j;

    // ---- service: stage z tile into zs4[buf] (transposed, pre-scaled) ----
#define STAGE(TIDX, BUF)                                                     \
    do {                                                                     \
        const float* __restrict__ zp_ = zlane + 96 * (TIDX);                 \
        _Pragma("unroll")                                                    \
        for (int tt = 0; tt < TILE; ++tt)                                    \
            ((float*)&zs4[BUF][tt >> 2][lane])[tt & 3] = Cc * zp_[3 * tt];   \
    } while (0)

    // ---- service: flush tile's (S,y) -> losses (Mahalanobis here) ----
#define FLUSH(TIDX, BUF)                                                     \
    do {                                                                     \
        const int tb_ = (TIDX) * TILE;                                       \
        _Pragma("unroll")                                                    \
        for (int rr = 0; rr < 6; ++rr) {                                     \
            const int ck_ = 4 * rr + fh;                                     \
            const bool ok_ = (ck_ < TRIPLES) && (traj0 + ck_ < n_traj);      \
            const float4 a0_ = sSM4[BUF][fb0 + 204 * rr];                    \
            const float4 a1_ = sSM4[BUF][fb0 + 204 * rr + SMS4];             \
            const float4 a2_ = sSM4[BUF][fb0 + 204 * rr + 2 * SMS4];         \
            const float m0e_ = (a0_.y * a0_.y) * frcp(a0_.x);                \
            const float m1e_ = (a1_.y * a1_.y) * frcp(a1_.x);                \
            const float m2e_ = (a2_.y * a2_.y) * frcp(a2_.x);                \
            const float m0o_ = (a0_.w * a0_.w) * frcp(a0_.z);                \
            const float m1o_ = (a1_.w * a1_.w) * frcp(a1_.z);                \
            const float m2o_ = (a2_.w * a2_.w) * frcp(a2_.z);                \
            const float l0_ = fmaf(m0e_ + m1e_ + m2e_, invCc2,               \
                                   (a0_.x * a1_.x) * a2_.x);                 \
            const float l1_ = fmaf(m0o_ + m1o_ + m2o_, invCc2,               \
                                   (a0_.z * a1_.z) * a2_.z);                 \
            if (ok_) *(float2*)(obase + tb_ + rr * (4 * T)) =                \
                make_float2(l0_, l1_);                                       \
        }                                                                    \
    } while (0)

    // ---- compute: one EKF step (23 VALU + 2 trans, single-rcp fusion) ----
#define STEP(ZZ, SS, YY)                                                     \
    do {                                                                     \
        const float zC   = (ZZ);                    /* Cc*z (pre-scaled) */  \
        const float e0   = exp2f(xv);               /* 2^(Cc*vel) */         \
        const float e    = fminf(e0, 1e30f);        /* saturation guard */   \
        const float u    = fmaf(DTc, p22, p02);                              \
        const float wp   = fmaf(DTc, p02, w);                                \
        const float S    = fmaf(DTc, u, wp);        /* = pp00 + r */         \
        const float P    = fmaf(e, S, S);           /* (e+1)*S */            \
        const float q_   = frcp(P);                 /* the ONE rcp */        \
        const float ie   = S * q_;                  /* ~ 1/(e+1) */          \
        const float rs   = fmaf(e, q_, q_);         /* ~ 1/S */              \
        const float t    = fmaf(-ie, ie, ie);       /* ie - ie^2 */          \
        const float a    = fmaf(m4cb, t, ca);                                \
        const float pp02 = fmaf(a, u, qc);                                   \
        const float ap   = a * p22;                                          \
        const float pp22 = fmaf(ap, a, qv);                                  \
        const float spC  = fmaf(DTc, xv, posC);                              \
        const float yvC  = zC - spC;                                         \
        const float rsyC = rs * yvC;                                         \
        const float sviC = fmaf(ca, xv, mcfCc);                              \
        const float svC  = fmaf(cf2Cc, ie, sviC);                            \
        xv   = fmaf(pp02, rsyC, svC);                                        \
        posC = fmaf(-r, rsyC, zC);                  /* = spC+(S-r)rs*y */    \
        w    = fmaf(nr2, rs, w0);                                            \
        const float k1 = pp02 * rs;                                          \
        p02 = r * k1;                                                        \
        p22 = fmaf(-k1, pp02, pp22);                                         \
        SS = S;                                                              \
        YY = yvC;                                                            \
    } while (0)

    int cur = 0;
    if (wid == 1) STAGE(0, 0);
    __syncthreads();

    #pragma unroll 1
    for (int tile = 0; tile < NT; ++tile) {
        if (wid == 0) {
            // (1) prefetch the whole tile's z into registers (one drain)
            float4 zq[TILE / 4];
            #pragma unroll
            for (int qq = 0; qq < TILE / 4; ++qq)
                zq[qq] = zs4[cur][qq][lane];
            float4* const smb = &sSM4[cur][lane * SMS4];
            // (2) 2 steps -> one inline ds_write_b128 (spread, no burst)
            #pragma unroll
            for (int h = 0; h < TILE / 2; ++h) {
                float s0_, y0_, s1_, y1_;
                const float za_ = ((const float*)&zq[h >> 1])[2 * (h & 1)];
                const float zb_ = ((const float*)&zq[h >> 1])[2 * (h & 1) + 1];
                STEP(za_, s0_, y0_);
                STEP(zb_, s1_, y1_);
                smb[h] = make_float4(s0_, y0_, s1_, y1_);
            }
        } else {
            if (tile + 1 < NT) STAGE(tile + 1, cur ^ 1);
            if (tile > 0)      FLUSH(tile - 1, cur ^ 1);
        }
        __syncthreads();                   // uniform: outside the role branch
        cur ^= 1;
    }
    if (wid == 1) FLUSH(NT - 1, cur ^ 1);  // last tile's buffer

#undef STEP
#undef FLUSH
#undef STAGE
}

extern "C" void kernel_launch(void* const* d_in, const int* in_sizes, int n_in,
                              void* d_out, int out_size, void* d_ws, size_t ws_size,
                              hipStream_t stream) {
    const float* meas = (const float*)d_in[0];
    const float* init_state = (const float*)d_in[1];
    const float* dyna = (const float*)d_in[2];
    const float* Qm  = (const float*)d_in[3];
    const float* Rm  = (const float*)d_in[4];
    const float* P0m = (const float*)d_in[5];
    float* out = (float*)d_out;

    const int n_traj = in_sizes[1] / 6;
    const int T = in_sizes[0] / (n_traj * 3);

    const int grid = (n_traj + TRIPLES - 1) / TRIPLES;
    ekf_kernel<<<grid, 128, 0, stream>>>(meas, init_state, dyna, Qm, Rm, P0m,
                                         out, n_traj, T);
}

// Round 11
// 102.196 us; speedup vs baseline: 1.0108x; 1.0108x over previous
//
#include <hip/hip_runtime.h>
#include <math.h>

// EKF over 2048 trajectories, T=512 serial steps; lane 3k+j = subsystem j of
// trajectory k (21 traj/wave), three independent 2-state/1-meas Kalman
// filters per trajectory. Latency-bound serial chain; wall = 512 x per-step.
//
// R14: producer/consumer wave specialization (~41 us warm).
// R15/R16/R17: pre-scaled z, service-side Mahalanobis; fused-rcp (flat ->
// trans issue at ~VALU cost); boundary smoothing + setprio (flat).
//
// R18 (this round): minimal 23-op step body. With trans == VALU cost (R16),
// the cheapest trans section is the plain 2-rcp form: e=exp2; ie=rcp(e+1);
// rs=rcp(S) - 4 ops, no fmin guard needed (e=inf -> ie=0 exactly). Fused-rcp
// (6 ops) and the R15 pp02 split reverted. 23 ops = exp2 + 2 rcp + 20 VALU;
// every op has a distinct algebraic role - this is the op-count floor for
// the recurrence. If flat: declare roofline (512 x max(issue, chain)).

#define TRIPLES 21
#define TILE    32
#define SMS4    17               // sSM row stride in float4 (16 pairs + 1 pad)

__device__ __forceinline__ float frcp(float x) { return __builtin_amdgcn_rcpf(x); }

__global__ __launch_bounds__(128, 1) void ekf_kernel(
    const float* __restrict__ meas,        // (n_traj, T, 3)
    const float* __restrict__ init_state,  // (n_traj, 6)
    const float* __restrict__ dyna,        // (4,)
    const float* __restrict__ Qm,          // (6,6)
    const float* __restrict__ Rm,          // (3,3)
    const float* __restrict__ P0m,         // (6,6)
    float* __restrict__ out,               // (n_traj*T,)
    int n_traj, int T)
{
    // z tiles (pre-scaled by Cc): [buf][t-chunk][compute-lane] float4 = 16 KB.
    __shared__ float4 zs4[2][TILE / 4][64];
    // (S,y) pairs: [buf][72 rows x SMS4] float4 = 39.2 KB (flush round rr=5
    // reads rows up to 71; stores guarded, reads in-bounds, rows>=63 garbage).
    __shared__ float4 sSM4[2][72 * SMS4];

    const int tid   = threadIdx.x;
    const int wid   = tid >> 6;            // 0 = compute, 1 = service
    const int lane  = tid & 63;
    const int k     = lane / 3;
    const int j     = lane - 3 * k;        // subsystem 0=x,1=y,2=theta
    const int traj0 = blockIdx.x * TRIPLES;
    const int kk    = (k < TRIPLES) ? k : (TRIPLES - 1);
    const int traj  = traj0 + kk;
    const int traj_eff = (traj < n_traj) ? traj : (n_traj - 1);

    const int NT = T / TILE;               // 16
    const int T3 = 3 * T;

    if (wid == 0) __builtin_amdgcn_s_setprio(1);   // favor the chain wave

    // ---- filter constants (theta block is linear: ca=1, cf=0) ----
    const float DTc = 1.0f / 120.0f;
    const float Cc  = 288.53900817779268f; // 200/ln2
    const float invCc2 = 1.0f / (Cc * Cc);
    const float fric = dyna[0], damp = dyna[1];
    const bool  lin = (j == 2);
    const float ca  = lin ? 1.0f : (1.0f - DTc * damp);
    const float cf  = lin ? 0.0f : (DTc * fric);
    const float cb  = 100.0f * cf;
    const float m4cb  = -4.0f * cb;
    const float cf2Cc = 2.0f * (cf * Cc);
    const float mcfCc = -(cf * Cc);
    const int pi = (j == 0) ? 0 : (j == 1) ? 1 : 4;
    const int vi = lin ? 5 : (pi + 2);     // theta velocity is state 5
    const float qp = Qm[pi * 7], qv = Qm[vi * 7], qc = Qm[pi * 6 + vi];
    const float r   = Rm[j * 4];
    const float nr2 = -r * r;
    const float w0  = r + r + qp;          // w' = nr2*rs + w0
    float p02 = P0m[pi * 6 + vi], p22 = P0m[vi * 7];
    float w   = P0m[pi * 7] + qp + r;      // w = p00 + qp + r (carried)
    float posC = Cc * init_state[traj_eff * 6 + pi];
    float xv   = Cc * init_state[traj_eff * 6 + vi];

    // ---- service-side invariants ----
    const int fh = lane >> 4;              // 0..3 traj row within flush round
    const int tw = lane & 15;              // t-pair index
    const int fb0 = (3 * fh) * SMS4 + tw;  // float4 index, rr=0, subsys 0
    float* const obase = out + (size_t)(traj0 + fh) * T + 2 * tw;
    const float* __restrict__ zlane = meas + (size_t)traj_eff * T3 + j;

    // ---- service: stage z tile into zs4[buf] (transposed, pre-scaled) ----
#define STAGE(TIDX, BUF)                                                     \
    do {                                                                     \
        const float* __restrict__ zp_ = zlane + 96 * (TIDX);                 \
        _Pragma("unroll")                                                    \
        for (int tt = 0; tt < TILE; ++tt)                                    \
            ((float*)&zs4[BUF][tt >> 2][lane])[tt & 3] = Cc * zp_[3 * tt];   \
    } while (0)

    // ---- service: flush tile's (S,y) -> losses (Mahalanobis here) ----
#define FLUSH(TIDX, BUF)                                                     \
    do {                                                                     \
        const int tb_ = (TIDX) * TILE;                                       \
        _Pragma("unroll")                                                    \
        for (int rr = 0; rr < 6; ++rr) {                                     \
            const int ck_ = 4 * rr + fh;                                     \
            const bool ok_ = (ck_ < TRIPLES) && (traj0 + ck_ < n_traj);      \
            const float4 a0_ = sSM4[BUF][fb0 + 204 * rr];                    \
            const float4 a1_ = sSM4[BUF][fb0 + 204 * rr + SMS4];             \
            const float4 a2_ = sSM4[BUF][fb0 + 204 * rr + 2 * SMS4];         \
            const float m0e_ = (a0_.y * a0_.y) * frcp(a0_.x);                \
            const float m1e_ = (a1_.y * a1_.y) * frcp(a1_.x);                \
            const float m2e_ = (a2_.y * a2_.y) * frcp(a2_.x);                \
            const float m0o_ = (a0_.w * a0_.w) * frcp(a0_.z);                \
            const float m1o_ = (a1_.w * a1_.w) * frcp(a1_.z);                \
            const float m2o_ = (a2_.w * a2_.w) * frcp(a2_.z);                \
            const float l0_ = fmaf(m0e_ + m1e_ + m2e_, invCc2,               \
                                   (a0_.x * a1_.x) * a2_.x);                 \
            const float l1_ = fmaf(m0o_ + m1o_ + m2o_, invCc2,               \
                                   (a0_.z * a1_.z) * a2_.z);                 \
            if (ok_) *(float2*)(obase + tb_ + rr * (4 * T)) =                \
                make_float2(l0_, l1_);                                       \
        }                                                                    \
    } while (0)

    // ---- compute: one EKF step (23 ops: exp2 + 2 rcp + 20 VALU) ----
#define STEP(ZZ, SS, YY)                                                     \
    do {                                                                     \
        const float zC   = (ZZ);                    /* Cc*z (pre-scaled) */  \
        const float e    = exp2f(xv);               /* 2^(Cc*vel) */         \
        const float ie   = frcp(e + 1.0f);          /* inf -> 0 exact */     \
        const float t    = fmaf(-ie, ie, ie);       /* ie - ie^2 */          \
        const float a    = fmaf(m4cb, t, ca);                                \
        const float u    = fmaf(DTc, p22, p02);                              \
        const float wp   = fmaf(DTc, p02, w);                                \
        const float S    = fmaf(DTc, u, wp);        /* = pp00 + r */         \
        const float rs   = frcp(S);                                          \
        const float spC  = fmaf(DTc, xv, posC);                              \
        const float yvC  = zC - spC;                                         \
        const float rsyC = rs * yvC;                                         \
        const float pp02 = fmaf(a, u, qc);                                   \
        const float ap   = a * p22;                                          \
        const float pp22 = fmaf(ap, a, qv);                                  \
        const float sviC = fmaf(ca, xv, mcfCc);                              \
        const float svC  = fmaf(cf2Cc, ie, sviC);                            \
        xv   = fmaf(pp02, rsyC, svC);                                        \
        posC = fmaf(-r, rsyC, zC);                  /* = spC+(S-r)rs*y */    \
        w    = fmaf(nr2, rs, w0);                                            \
        const float k1 = pp02 * rs;                                          \
        p02 = r * k1;                                                        \
        p22 = fmaf(-k1, pp02, pp22);                                         \
        SS = S;                                                              \
        YY = yvC;                                                            \
    } while (0)

    int cur = 0;
    if (wid == 1) STAGE(0, 0);
    __syncthreads();

    #pragma unroll 1
    for (int tile = 0; tile < NT; ++tile) {
        if (wid == 0) {
            // prefetch the whole tile's z into registers (one drain)
            float4 zq[TILE / 4];
            #pragma unroll
            for (int qq = 0; qq < TILE / 4; ++qq)
                zq[qq] = zs4[cur][qq][lane];
            float4* const smb = &sSM4[cur][lane * SMS4];
            // 2 steps -> one inline ds_write_b128 (spread, no burst)
            #pragma unroll
            for (int h = 0; h < TILE / 2; ++h) {
                float s0_, y0_, s1_, y1_;
                const float za_ = ((const float*)&zq[h >> 1])[2 * (h & 1)];
                const float zb_ = ((const float*)&zq[h >> 1])[2 * (h & 1) + 1];
                STEP(za_, s0_, y0_);
                STEP(zb_, s1_, y1_);
                smb[h] = make_float4(s0_, y0_, s1_, y1_);
            }
        } else {
            if (tile + 1 < NT) STAGE(tile + 1, cur ^ 1);
            if (tile > 0)      FLUSH(tile - 1, cur ^ 1);
        }
        __syncthreads();                   // uniform: outside the role branch
        cur ^= 1;
    }
    if (wid == 1) FLUSH(NT - 1, cur ^ 1);  // last tile's buffer

#undef STEP
#undef FLUSH
#undef STAGE
}

extern "C" void kernel_launch(void* const* d_in, const int* in_sizes, int n_in,
                              void* d_out, int out_size, void* d_ws, size_t ws_size,
                              hipStream_t stream) {
    const float* meas = (const float*)d_in[0];
    const float* init_state = (const float*)d_in[1];
    const float* dyna = (const float*)d_in[2];
    const float* Qm  = (const float*)d_in[3];
    const float* Rm  = (const float*)d_in[4];
    const float* P0m = (const float*)d_in[5];
    float* out = (float*)d_out;

    const int n_traj = in_sizes[1] / 6;
    const int T = in_sizes[0] / (n_traj * 3);

    const int grid = (n_traj + TRIPLES - 1) / TRIPLES;
    ekf_kernel<<<grid, 128, 0, stream>>>(meas, init_state, dyna, Qm, Rm, P0m,
                                         out, n_traj, T);
}